// Round 5
// baseline (153.096 us; speedup 1.0000x reference)
//
#include <hip/hip_runtime.h>
#include <hip/hip_bf16.h>
#include <stdint.h>

#define NSK 1000
#define DD 64
#define MM 64
#define BB 64
#define TT 200

// broadcast lane l's value to all lanes via v_readlane (l compile-time constant)
__device__ __forceinline__ float lane_bcast(float v, int l) {
  return __uint_as_float(__builtin_amdgcn_readlane(__float_as_uint(v), l));
}

// Pass A: per (b,t) row: w = softmax(k·Mk^T), e = sigmoid(v·eW^T+eb), a = tanh(v·aW^T+ab)
// Weights staged in LDS (quad-rotation swizzle). Weight rows are register-cached in
// quarters and REUSED across the wave's 4 rows (LDS traffic /4 vs round 4).
__global__ __launch_bounds__(256) void wea_kernel(
    const int* __restrict__ skills, const int* __restrict__ responses,
    const float* __restrict__ k_emb, const float* __restrict__ v_emb,
    const float* __restrict__ Mk, const float* __restrict__ eW,
    const float* __restrict__ eb, const float* __restrict__ aW,
    const float* __restrict__ ab,
    float* __restrict__ w_ws, float* __restrict__ e_ws, float* __restrict__ a_ws)
{
  __shared__ float sMk[4096], seW[4096], saW[4096];
  const int tid = threadIdx.x;
  for (int Q = tid; Q < 1024; Q += 256) {          // 1024 quads per 64x64 matrix
    const int j = Q >> 4, c = Q & 15;
    const int dst = j * 64 + ((c + j) & 15) * 4;
    *(float4*)&sMk[dst] = ((const float4*)Mk)[Q];
    *(float4*)&seW[dst] = ((const float4*)eW)[Q];
    *(float4*)&saW[dst] = ((const float4*)aW)[Q];
  }
  __syncthreads();

  const int wave = tid >> 6, lane = tid & 63;
  const float ebl = eb[lane], abl = ab[lane];

  // issue all 4 rows' gather chains up-front
  float kvs[4], vvs[4];
  #pragma unroll
  for (int i = 0; i < 4; ++i) {
    const int row = blockIdx.x * 16 + wave * 4 + i;
    const int sk = skills[row];
    int r = responses[row]; r = (r > -1) ? r : 0;   // masked_r
    kvs[i] = k_emb[(size_t)sk * DD + lane];
    vvs[i] = v_emb[(size_t)(sk + NSK * r) * DD + lane];
  }

  float accK[4] = {0.f, 0.f, 0.f, 0.f};
  float accE[4] = {0.f, 0.f, 0.f, 0.f};
  float accA[4] = {0.f, 0.f, 0.f, 0.f};
  #pragma unroll 1
  for (int h = 0; h < 4; ++h) {                    // quarters: 4 c's each
    float4 qm[4], qe[4], qa[4];                    // 48 VGPR live
    #pragma unroll
    for (int c = 0; c < 4; ++c) {
      const int cc = h * 4 + c;
      const int off = lane * 64 + ((cc + lane) & 15) * 4;
      qm[c] = *(const float4*)&sMk[off];
      qe[c] = *(const float4*)&seW[off];
      qa[c] = *(const float4*)&saW[off];
    }
    #pragma unroll
    for (int i = 0; i < 4; ++i) {
      #pragma unroll
      for (int c = 0; c < 4; ++c) {
        const float mm[4] = {qm[c].x, qm[c].y, qm[c].z, qm[c].w};
        const float ee[4] = {qe[c].x, qe[c].y, qe[c].z, qe[c].w};
        const float aa[4] = {qa[c].x, qa[c].y, qa[c].z, qa[c].w};
        #pragma unroll
        for (int j = 0; j < 4; ++j) {
          const int d = (h * 4 + c) * 4 + j;
          const float kd = lane_bcast(kvs[i], d);
          const float vd = lane_bcast(vvs[i], d);
          accK[i] = fmaf(kd, mm[j], accK[i]);
          accE[i] = fmaf(vd, ee[j], accE[i]);
          accA[i] = fmaf(vd, aa[j], accA[i]);
        }
      }
    }
  }

  #pragma unroll
  for (int i = 0; i < 4; ++i) {
    const int row = blockIdx.x * 16 + wave * 4 + i;   // grid exact: 800*16 = 12800
    float mx = accK[i];
    #pragma unroll
    for (int off = 32; off; off >>= 1) mx = fmaxf(mx, __shfl_xor(mx, off));
    float ex = __expf(accK[i] - mx);
    float sm = ex;
    #pragma unroll
    for (int off = 32; off; off >>= 1) sm += __shfl_xor(sm, off);
    w_ws[(size_t)row * 64 + lane] = ex / sm;
    e_ws[(size_t)row * 64 + lane] = 1.f / (1.f + __expf(-(accE[i] + ebl)));
    a_ws[(size_t)row * 64 + lane] = tanhf(accA[i] + abl);
  }
}

// ---- scan helpers: chunked register double-buffer (depth CH=8 steps) ----
#define CH 8
#define RW 8   // Mv rows per wave

__device__ __forceinline__ void load_chunk(
    const float* __restrict__ wr, const float* __restrict__ er,
    const float* __restrict__ ar, int t0, int wl, int lane,
    float* wb, float* ebf, float* abf)
{
  #pragma unroll
  for (int k = 0; k < CH; ++k) {
    wb[k]  = wr[(t0 + k) * 64 + wl];
    ebf[k] = er[(t0 + k) * 64 + lane];
    abf[k] = ar[(t0 + k) * 64 + lane];
  }
}

__device__ __forceinline__ void compute_chunk(
    float* Mv, const float* wb, const float* ebf, const float* abf,
    int t0, int part, int lane, float* __restrict__ pr)
{
  #pragma unroll
  for (int k = 0; k < CH; ++k) {
    const float wv = wb[k], ev = ebf[k], av = abf[k];
    float rp = 0.f;
    #pragma unroll
    for (int i = 0; i < RW; ++i) {
      float wm = lane_bcast(wv, i);        // w[m0+i] sits in lane i (0..RW-1)
      rp = fmaf(wm, Mv[i], rp);            // read uses PRE-update Mv
      float tp = fmaf(-ev, Mv[i], av);     // a - e*Mv
      Mv[i] = fmaf(wm, tp, Mv[i]);         // Mv += w*(a - e*Mv)
    }
    pr[(t0 + k) * 512 + part * 64 + lane] = rp;  // per-wave partial of read[d]
  }
}

// Pass B: sequential scan. Mv rows are INDEPENDENT (row m uses only w[m],e[d],a[d]),
// so each batch is split over 2 blocks x 4 waves x 8 rows (128 blocks total).
// read-reduction across the 8 per-wave partials is DEFERRED to pass C.
__global__ __launch_bounds__(256) void scan_kernel(
    const float* __restrict__ Mv0,
    const float* __restrict__ w_ws, const float* __restrict__ e_ws,
    const float* __restrict__ a_ws, float* __restrict__ part_ws)
{
  const int b    = blockIdx.x >> 1;
  const int s    = blockIdx.x & 1;
  const int wave = threadIdx.x >> 6;
  const int lane = threadIdx.x & 63;
  const int m0   = s * 32 + wave * RW;
  const int part = s * 4 + wave;
  const int wl   = m0 + (lane & (RW - 1));
  float Mv[RW];
  #pragma unroll
  for (int i = 0; i < RW; ++i) Mv[i] = Mv0[(size_t)(m0 + i) * DD + lane];

  const float* wr = w_ws + (size_t)b * TT * 64;
  const float* er = e_ws + (size_t)b * TT * 64;
  const float* ar = a_ws + (size_t)b * TT * 64;
  float* pr = part_ws + (size_t)b * TT * 512;

  float wb0[CH], eb0[CH], ab0[CH];
  float wb1[CH], eb1[CH], ab1[CH];
  load_chunk(wr, er, ar, 0, wl, lane, wb0, eb0, ab0);

  // TT/CH = 25 chunks; manual 2-unroll so buffer selection is compile-time
  for (int ch = 0; ch < TT / CH; ch += 2) {
    if ((ch + 1) * CH < TT)
      load_chunk(wr, er, ar, (ch + 1) * CH, wl, lane, wb1, eb1, ab1);
    compute_chunk(Mv, wb0, eb0, ab0, ch * CH, part, lane, pr);
    if ((ch + 2) * CH < TT)
      load_chunk(wr, er, ar, (ch + 2) * CH, wl, lane, wb0, eb0, ab0);
    if ((ch + 1) * CH < TT)
      compute_chunk(Mv, wb1, eb1, ab1, (ch + 1) * CH, part, lane, pr);
  }
}

// Pass C: per (b, t>=1) row: read = sum of 8 partials; f = tanh([read,k]·fW^T + fb);
// p = sigmoid(f·pW + pb). fW rows register-cached in quarters, reused across 4 rows.
__global__ __launch_bounds__(256) void fp_kernel(
    const int* __restrict__ skills, const float* __restrict__ k_emb,
    const float* __restrict__ fW, const float* __restrict__ fb,
    const float* __restrict__ pW, const float* __restrict__ pb,
    const float* __restrict__ part_ws, float* __restrict__ out)
{
  __shared__ float sfW[8192];
  const int tid = threadIdx.x;
  for (int Q = tid; Q < 2048; Q += 256) {          // 2048 quads in 64x128 fW
    const int j = Q >> 5, c = Q & 31;
    *(float4*)&sfW[j * 128 + ((c + j) & 31) * 4] = ((const float4*)fW)[Q];
  }
  __syncthreads();

  const int wave = tid >> 6, lane = tid & 63;
  const float fbl = fb[lane];
  const float pwl = pW[lane];
  const float pb0 = pb[0];

  // issue all 4 rows' loads up-front
  float rvs[4], kvs[4];
  #pragma unroll
  for (int i = 0; i < 4; ++i) {
    const int idx = blockIdx.x * 16 + wave * 4 + i;
    const int b   = idx / (TT - 1);
    const int tm1 = idx % (TT - 1);
    const int row = b * TT + tm1 + 1;
    const float* pp = part_ws + (size_t)row * 512;
    float r0 = pp[lane]       + pp[64 + lane];
    float r1 = pp[128 + lane] + pp[192 + lane];
    float r2 = pp[256 + lane] + pp[320 + lane];
    float r3 = pp[384 + lane] + pp[448 + lane];
    rvs[i] = (r0 + r1) + (r2 + r3);
    kvs[i] = k_emb[(size_t)skills[row] * DD + lane];
  }

  float acc[4] = {fbl, fbl, fbl, fbl};
  #pragma unroll 1
  for (int h = 0; h < 4; ++h) {                    // quarters: 8 c's each
    float4 qf[8];                                  // 32 VGPR live
    #pragma unroll
    for (int c = 0; c < 8; ++c) {
      const int cc = h * 8 + c;
      qf[c] = *(const float4*)&sfW[lane * 128 + ((cc + lane) & 31) * 4];
    }
    #pragma unroll
    for (int i = 0; i < 4; ++i) {
      #pragma unroll
      for (int c = 0; c < 8; ++c) {
        const float ww[4] = {qf[c].x, qf[c].y, qf[c].z, qf[c].w};
        #pragma unroll
        for (int j = 0; j < 4; ++j) {
          const int d = (h * 8 + c) * 4 + j;
          const float sv = (d < 64) ? lane_bcast(rvs[i], d) : lane_bcast(kvs[i], d - 64);
          acc[i] = fmaf(sv, ww[j], acc[i]);
        }
      }
    }
  }

  #pragma unroll
  for (int i = 0; i < 4; ++i) {
    const int idx = blockIdx.x * 16 + wave * 4 + i;  // grid exact: 796*16 = 12736
    const int b   = idx / (TT - 1);
    const int tm1 = idx % (TT - 1);
    float fj = tanhf(acc[i]);
    float prod = fj * pwl;
    #pragma unroll
    for (int off = 32; off; off >>= 1) prod += __shfl_xor(prod, off);
    float p = 1.f / (1.f + __expf(-(prod + pb0)));
    if (lane == 0) out[(size_t)b * (TT - 1) + tm1] = p;
  }
}

extern "C" void kernel_launch(void* const* d_in, const int* in_sizes, int n_in,
                              void* d_out, int out_size, void* d_ws, size_t ws_size,
                              hipStream_t stream) {
  const int* skills    = (const int*)d_in[0];
  const int* responses = (const int*)d_in[1];
  const float* k_emb   = (const float*)d_in[2];
  const float* v_emb   = (const float*)d_in[3];
  const float* Mk      = (const float*)d_in[4];
  const float* Mv0     = (const float*)d_in[5];
  const float* fW      = (const float*)d_in[6];
  const float* fb      = (const float*)d_in[7];
  const float* eW      = (const float*)d_in[8];
  const float* eb      = (const float*)d_in[9];
  const float* aW      = (const float*)d_in[10];
  const float* ab      = (const float*)d_in[11];
  const float* pW      = (const float*)d_in[12];
  const float* pb      = (const float*)d_in[13];

  // fp32 scratch: w | e | a (B*T*64 each) | read-partials (B*T*512) ~= 36 MB
  float* w_ws    = (float*)d_ws;
  float* e_ws    = w_ws + (size_t)BB * TT * 64;
  float* a_ws    = e_ws + (size_t)BB * TT * 64;
  float* part_ws = a_ws + (size_t)BB * TT * 64;

  wea_kernel<<<dim3(BB * TT / 16), 256, 0, stream>>>(
      skills, responses, k_emb, v_emb, Mk, eW, eb, aW, ab, w_ws, e_ws, a_ws);
  scan_kernel<<<dim3(BB * 2), 256, 0, stream>>>(Mv0, w_ws, e_ws, a_ws, part_ws);
  fp_kernel<<<dim3(BB * (TT - 1) / 16), 256, 0, stream>>>(
      skills, k_emb, fW, fb, pW, pb, part_ws, (float*)d_out);
}